// Round 18
// baseline (647.761 us; speedup 1.0000x reference)
//
#include <hip/hip_runtime.h>
#include <math.h>

#define N_ATOMS 60000
#define M_NBR   12
#define D_FEA   64
#define NBR_FEA 41
#define B_CRY   1200
#define NA_CRY  50
#define EPSV    1e-5f

#define NBLK_MAIN 2048   // blocks for k_stats (4 waves each)

__device__ __forceinline__ float wsum(float v){
#pragma unroll
  for (int o = 32; o > 0; o >>= 1) v += __shfl_xor(v, o, 64);
  return v;
}
__device__ __forceinline__ float wmax64(float v){
#pragma unroll
  for (int o = 32; o > 0; o >>= 1) v = fmaxf(v, __shfl_xor(v, o, 64));
  return v;
}
__device__ __forceinline__ float softplusf(float x){
  return fmaxf(x, 0.f) + __logf(1.f + __expf(-fabsf(x)));
}
__device__ __forceinline__ float sigmoidf(float x){
  return 1.f / (1.f + __expf(-x));
}
// round-to-nearest-even fp32 -> bf16 bits (low 16)
__device__ __forceinline__ unsigned bf16_rne(float x){
  unsigned u = __float_as_uint(x);
  return (u + 0x7fffu + ((u >> 16) & 1u)) >> 16;
}
__device__ __forceinline__ unsigned pack2(float lo, float hi){
  return bf16_rne(lo) | (bf16_rne(hi) << 16);
}
__device__ __forceinline__ float unlo(unsigned u){ return __uint_as_float(u << 16); }
__device__ __forceinline__ float unhi(unsigned u){ return __uint_as_float(u & 0xffff0000u); }
// wave-uniform lane broadcast via SGPR path (bit-cast: readlane is i32-typed)
__device__ __forceinline__ float rdl(float v, int l){
  return __uint_as_float(__builtin_amdgcn_readlane(__float_as_uint(v), l));
}

// ---------------- K1: transformer + fused projections -----------------------
// r16 structure (register rows + readlane broadcast, 3 barriers, bf16 srcT).
// r17 BUG FIX: score lo-half used unlo(u<<16>>16<<16) which double-shifts the
// low bf16 out of the word (even channels zeroed, absmax 1.06). unlo(u) IS
// the lo-half decode; unhi(u) the hi-half.
__global__ __launch_bounds__(512, 8) void k_transformer(
    const float* __restrict__ atom_in, const float* __restrict__ adj,
    const float* __restrict__ w1, const float* __restrict__ b1,
    const float* __restrict__ w2, const float* __restrict__ b2,
    const float* __restrict__ g1v, const float* __restrict__ be1,
    const float* __restrict__ g2v, const float* __restrict__ be2,
    const int* __restrict__ cidx, const float* __restrict__ fc_w,
    const float* __restrict__ fc_b, float* __restrict__ atom_tf,
    unsigned* __restrict__ proj1p, unsigned* __restrict__ proj2p)
{
  __shared__ float    s_a[NA_CRY * D_FEA];   // src rows; later atom_in rows
  __shared__ float    s_c[NA_CRY * D_FEA];   // LN1 rows; later LN2 rows
  __shared__ unsigned s_t2[32 * NA_CRY];     // srcT bf16 pairs: [d>>1][i], lo=even d
  __shared__ int      s_gi[NA_CRY];          // gathered atom ids

  const int tid  = threadIdx.x;
  const int b    = blockIdx.x;
  const int lane = tid & 63;
  const int w    = tid >> 6;   // 0..7

  // phase 1: gather src -> s_a; bf16-pair transposed copy -> s_t2; ids
  if (tid < NA_CRY) s_gi[tid] = cidx[b * NA_CRY + tid];
  {
    unsigned short* st = (unsigned short*)s_t2;
    for (int p = tid; p < NA_CRY * D_FEA; p += 512){
      int i = p >> 6, d = p & 63;
      float v = atom_in[(size_t)cidx[b * NA_CRY + i] * D_FEA + d];
      s_a[p] = v;
      st[(d >> 1) * (2 * NA_CRY) + i * 2 + (d & 1)] = (unsigned short)bf16_rne(v);
    }
  }
  __syncthreads();

  // phase 2+3+4+5 fused, one row per iteration:
  //   score row n (readlane(ai) x s_t2 bf16 pairs) -> softmax in regs -> av
  //   x row n = src[n] + attn @ src  (50 conflict-free s_a column reads)
  //   LN1 -> s_c[n]
  const float scale = 0.125f; // 1/sqrt(64)
  const int jc = (lane < NA_CRY) ? lane : NA_CRY - 1;
  for (int n = w; n < NA_CRY; n += 8){
    float ai = s_a[n * D_FEA + lane];          // lane d holds src[n][d]
    float ac0 = 0.f, ac1 = 0.f;
#pragma unroll 4
    for (int dp = 0; dp < 32; ++dp){
      unsigned u = s_t2[dp * NA_CRY + jc];     // (src[2dp][jc], src[2dp+1][jc])
      ac0 += rdl(ai, 2 * dp)     * unlo(u);    // FIXED: unlo(u) decodes lo half
      ac1 += rdl(ai, 2 * dp + 1) * unhi(u);
    }
    float sc_ = (ac0 + ac1) * scale * adj[(size_t)b * NA_CRY * NA_CRY + n * NA_CRY + jc];
    float v  = (lane < NA_CRY) ? sc_ : -1e30f;
    float mx = wmax64(v);
    float e  = (lane < NA_CRY) ? __expf(v - mx) : 0.f;
    float av = e / wsum(e);                    // attn[n][lane] in reg

    float xv = ai;                             // residual src[n][lane]
#pragma unroll 4
    for (int m = 0; m < NA_CRY; ++m)
      xv += rdl(av, m) * s_a[m * D_FEA + lane];

    float mu  = wsum(xv) * (1.f / 64.f);
    float dx  = xv - mu;
    float var = wsum(dx * dx) * (1.f / 64.f);
    s_c[n * D_FEA + lane] = dx * rsqrtf(var + EPSV) * g1v[lane] + be1[lane];
  }
  __syncthreads();   // all src reads done -> s_a reusable

  // phase 9a: gather atom_in rows into s_a (src dead)
  for (int p = tid; p < NA_CRY * D_FEA; p += 512){
    int i = p >> 6, d = p & 63;
    s_a[p] = atom_in[(size_t)s_gi[i] * D_FEA + d];
  }

  // phase 6+7+8 fused per row: h1 -> t -> LN2 (register-resident; weights
  // from L1-coalesced global). LN2 overwrites own s_c row.
  for (int n = w; n < NA_CRY; n += 8){
    float a_n = s_c[n * D_FEA + lane];         // LN1 row value (lane = channel)
    float h0 = b1[lane], h1v = 0.f;
#pragma unroll 4
    for (int k = 0; k < D_FEA; k += 2){
      h0  += rdl(a_n, k)     * w1[k * D_FEA + lane];
      h1v += rdl(a_n, k + 1) * w1[(k + 1) * D_FEA + lane];
    }
    float h = fmaxf(h0 + h1v, 0.f);            // h1[n][lane]
    float t0 = b2[lane], t1 = 0.f;
#pragma unroll 4
    for (int k = 0; k < D_FEA; k += 2){
      t0 += rdl(h, k)     * w2[k * D_FEA + lane];
      t1 += rdl(h, k + 1) * w2[(k + 1) * D_FEA + lane];
    }
    float t = a_n + t0 + t1;
    float mu  = wsum(t) * (1.f / 64.f);
    float dx  = t - mu;
    float var = wsum(dx * dx) * (1.f / 64.f);
    float res = dx * rsqrtf(var + EPSV) * g2v[lane] + be2[lane];
    atom_tf[(size_t)(b * NA_CRY + n) * D_FEA + lane] = res;
    s_c[n * D_FEA + lane] = res;               // own row: LN1 dead, safe
  }
  __syncthreads();   // s_a (atom_in rows) ready for all waves

  // phase 9b: projections per row (register broadcast; fc_w L1-coalesced)
  for (int n = w; n < NA_CRY; n += 8){
    float t_n = s_c[n * D_FEA + lane];         // LN2 row
    float s_n = s_a[n * D_FEA + lane];         // atom_in row
    float A = fc_b[lane], Bv = fc_b[64 + lane], C = 0.f, Dv = 0.f;
#pragma unroll 4
    for (int k = 0; k < D_FEA; ++k){
      float tv = rdl(t_n, k), sv = rdl(s_n, k);
      A  += tv * fc_w[k * 128 + lane];
      Bv += tv * fc_w[k * 128 + 64 + lane];
      C  += sv * fc_w[(64 + k) * 128 + lane];
      Dv += sv * fc_w[(64 + k) * 128 + 64 + lane];
    }
    proj1p[(size_t)(b * NA_CRY + n) * 64 + lane] = pack2(A, Bv);
    proj2p[(size_t)s_gi[n] * 64 + lane] = pack2(C, Dv);
  }
}

// ---------------- K3: BN1 stats + store pre-BN g (bf16x2) -------------------
// (r16 proven: global_load_lds staging into wave-private dbuf LDS tile.)
#define LOADRW(MM) unsigned rw##MM = proj2p[(size_t)__builtin_amdgcn_readfirstlane(jrow[MM]) * 64 + lane];

#define STAGE(AA, BUF) { \
    const float* srcp = nbr_fea + (size_t)(AA) * (M_NBR * NBR_FEA); \
    float* dstp = s_frow + (w * 2 + (BUF)) * 512; \
    _Pragma("unroll") \
    for (int t = 0; t < 7; ++t) \
      __builtin_amdgcn_global_load_lds(srcp + t * 64 + lane, dstp + t * 64, 4, 0, 0); \
    if (lane < 44) \
      __builtin_amdgcn_global_load_lds(srcp + 448 + lane, dstp + 448, 4, 0, 0); \
  }

#define GBODY(MM) { \
    float g0 = p10 + unlo(rw##MM); \
    float g1 = p11 + unhi(rw##MM); \
    _Pragma("unroll") \
    for (int k = 0; k < NBR_FEA; ++k){ \
      float aa = fr[MM * NBR_FEA + k]; \
      g0 += aa * unlo(wbp[k]); \
      g1 += aa * unhi(wbp[k]); \
    } \
    if (STORE) gated[(size_t)(base + MM) * 64 + lane] = pack2(g0, g1); \
    s0 += g0; q0 += g0 * g0; \
    s1 += g1; q1 += g1 * g1; }

template<int STORE>
__global__ __launch_bounds__(256) void k_stats(
    const float* __restrict__ nbr_fea, const int* __restrict__ nbr_idx,
    const float* __restrict__ fc_w, const unsigned* __restrict__ proj1p,
    const unsigned* __restrict__ proj2p, float* __restrict__ part1,
    unsigned* __restrict__ gated)
{
  __shared__ float red[1024];
  __shared__ float s_frow[4 * 2 * 512];  // 4 waves x double-buffer x 512 floats
  const int tid = threadIdx.x, lane = tid & 63, w = tid >> 6;

  unsigned wbp[NBR_FEA];
#pragma unroll
  for (int k = 0; k < NBR_FEA; ++k){
    float w0 = fc_w[(128 + k) * 128 + lane];
    float w1 = fc_w[(128 + k) * 128 + 64 + lane];
    wbp[k] = pack2(w0, w1);
  }

  const int gw = blockIdx.x * 4 + w, nw = gridDim.x * 4;
  const int q = N_ATOMS / nw, rr = N_ATOMS % nw;
  const int a0 = gw * q + (gw < rr ? gw : rr);
  const int a1 = a0 + q + (gw < rr ? 1 : 0);
  float s0 = 0.f, s1 = 0.f, q0 = 0.f, q1 = 0.f;
  int cur = 0;
  if (a0 < a1){ STAGE(a0, 0); }
  for (int a = a0; a < a1; ++a){
    const int au = __builtin_amdgcn_readfirstlane(a);
    const int base = au * M_NBR;
    const int* jrow = nbr_idx + base;            // uniform -> s_load (tiny)
    unsigned p1v = proj1p[(size_t)au * 64 + lane];
    LOADRW(0) LOADRW(1) LOADRW(2) LOADRW(3) LOADRW(4) LOADRW(5)
    LOADRW(6) LOADRW(7) LOADRW(8) LOADRW(9) LOADRW(10) LOADRW(11)
    const int anext = (a + 1 < a1) ? (a + 1) : a;
    STAGE(anext, cur ^ 1);                       // 8 newest vmem ops
    asm volatile("s_waitcnt vmcnt(8)" ::: "memory");  // drain rw/p1 + prior stage
    const float* fr = s_frow + (w * 2 + cur) * 512;
    const float p10 = unlo(p1v), p11 = unhi(p1v);
    GBODY(0) GBODY(1) GBODY(2) GBODY(3) GBODY(4) GBODY(5)
    GBODY(6) GBODY(7) GBODY(8) GBODY(9) GBODY(10) GBODY(11)
    cur ^= 1;
  }
  red[w * 256 + lane]        = s0;
  red[w * 256 + 64 + lane]   = s1;
  red[w * 256 + 128 + lane]  = q0;
  red[w * 256 + 192 + lane]  = q1;
  __syncthreads();
  float v = red[tid] + red[256 + tid] + red[512 + tid] + red[768 + tid];
  part1[blockIdx.x * 256 + tid] = v;   // [0:128]=sum(ch), [128:256]=sumsq(ch)
}

// finish BN1 stats: stats1[c]=scale, stats1[128+c]=shift
__global__ __launch_bounds__(1024) void k_stats_fin(
    const float* __restrict__ part1, const float* __restrict__ bn1_g,
    const float* __restrict__ bn1_b, float* __restrict__ stats1)
{
  __shared__ float red2[4 * 256];
  __shared__ float col[256];
  const int tid = threadIdx.x;
  const int c = tid & 255, g = tid >> 8;  // 4 groups
  float v = 0.f;
  for (int b = g; b < NBLK_MAIN; b += 4) v += part1[b * 256 + c];
  red2[g * 256 + c] = v;
  __syncthreads();
  if (g == 0) col[c] = red2[c] + red2[256 + c] + red2[512 + c] + red2[768 + c];
  __syncthreads();
  if (tid < 128){
    const float inv = 1.f / (float)(N_ATOMS * M_NBR);
    float mu = col[tid] * inv;
    float var = col[128 + tid] * inv - mu * mu;
    float sc = bn1_g[tid] * rsqrtf(var + EPSV);
    stats1[tid] = sc;
    stats1[128 + tid] = bn1_b[tid] - mu * sc;
  }
}

// ---------------- K4a (gated path): streaming BN1+gate+sum ------------------
__global__ __launch_bounds__(256) void k_reduce_g(
    const unsigned* __restrict__ gated, const float* __restrict__ stats1,
    float* __restrict__ nbr_sumed, float* __restrict__ part2)
{
  __shared__ float red[512];
  const int tid = threadIdx.x, lane = tid & 63, w = tid >> 6;
  const float sc0 = stats1[lane],       sc1 = stats1[64 + lane];
  const float tc0 = stats1[128 + lane], tc1 = stats1[192 + lane];
  const int wg = blockIdx.x * 4 + w, nw = gridDim.x * 4;
  float bs = 0.f, bq = 0.f;
  for (int a = wg; a < N_ATOMS; a += nw){
    const size_t base = (size_t)a * M_NBR * 64 + lane;
    float acc = 0.f;
#pragma unroll
    for (int m = 0; m < M_NBR; ++m){
      unsigned gv = gated[base + m * 64];
      acc += sigmoidf(unlo(gv) * sc0 + tc0) * softplusf(unhi(gv) * sc1 + tc1);
    }
    nbr_sumed[(size_t)a * 64 + lane] = acc;
    bs += acc; bq += acc * acc;
  }
  red[w * 128 + lane]      = bs;
  red[w * 128 + 64 + lane] = bq;
  __syncthreads();
  if (tid < 128){
    float v = red[tid] + red[128 + tid] + red[256 + tid] + red[384 + tid];
    part2[blockIdx.x * 128 + tid] = v;  // [0:64]=sum, [64:128]=sumsq
  }
}

// ---------------- K4b (fallback): recompute g, BN1, gate, sum ---------------
#define GBODYR(MM) { \
    const float* frow = nbr_fea + (size_t)(base + MM) * NBR_FEA; \
    float g0 = p10 + unlo(rw##MM); \
    float g1 = p11 + unhi(rw##MM); \
    _Pragma("unroll") \
    for (int k = 0; k < NBR_FEA; ++k){ \
      float aa = frow[k]; \
      g0 += aa * unlo(wbp[k]); \
      g1 += aa * unhi(wbp[k]); \
    } \
    acc += sigmoidf(g0 * sc0 + tc0) * softplusf(g1 * sc1 + tc1); }

__global__ __launch_bounds__(256) void k_reduce_r(
    const float* __restrict__ nbr_fea, const int* __restrict__ nbr_idx,
    const float* __restrict__ fc_w, const unsigned* __restrict__ proj1p,
    const unsigned* __restrict__ proj2p, const float* __restrict__ stats1,
    float* __restrict__ nbr_sumed, float* __restrict__ part2)
{
  __shared__ float red[512];
  const int tid = threadIdx.x, lane = tid & 63, w = tid >> 6;
  unsigned wbp[NBR_FEA];
#pragma unroll
  for (int k = 0; k < NBR_FEA; ++k){
    float w0 = fc_w[(128 + k) * 128 + lane];
    float w1 = fc_w[(128 + k) * 128 + 64 + lane];
    wbp[k] = pack2(w0, w1);
  }
  const float sc0 = stats1[lane],       sc1 = stats1[64 + lane];
  const float tc0 = stats1[128 + lane], tc1 = stats1[192 + lane];
  const int gw = blockIdx.x * 4 + w, nw = gridDim.x * 4;
  const int q = N_ATOMS / nw, rr = N_ATOMS % nw;
  const int a0 = gw * q + (gw < rr ? gw : rr);
  const int a1 = a0 + q + (gw < rr ? 1 : 0);
  float bs = 0.f, bq = 0.f;
  for (int a = a0; a < a1; ++a){
    const int au = __builtin_amdgcn_readfirstlane(a);
    const int base = au * M_NBR;
    const int* jrow = nbr_idx + base;
    unsigned p1v = proj1p[(size_t)au * 64 + lane];
    LOADRW(0) LOADRW(1) LOADRW(2) LOADRW(3) LOADRW(4) LOADRW(5)
    LOADRW(6) LOADRW(7) LOADRW(8) LOADRW(9) LOADRW(10) LOADRW(11)
    const float p10 = unlo(p1v), p11 = unhi(p1v);
    float acc = 0.f;
    GBODYR(0) GBODYR(1) GBODYR(2) GBODYR(3) GBODYR(4) GBODYR(5)
    GBODYR(6) GBODYR(7) GBODYR(8) GBODYR(9) GBODYR(10) GBODYR(11)
    nbr_sumed[(size_t)au * 64 + lane] = acc;
    bs += acc; bq += acc * acc;
  }
  red[w * 128 + lane]      = bs;
  red[w * 128 + 64 + lane] = bq;
  __syncthreads();
  if (tid < 128){
    float v = red[tid] + red[128 + tid] + red[256 + tid] + red[384 + tid];
    part2[blockIdx.x * 128 + tid] = v;
  }
}

// finish BN2 stats
__global__ __launch_bounds__(1024) void k_red_fin(
    const float* __restrict__ part2, const float* __restrict__ bn2_g,
    const float* __restrict__ bn2_b, float* __restrict__ stats2)
{
  __shared__ float red2[8 * 128];
  __shared__ float col[128];
  const int tid = threadIdx.x;
  const int c = tid & 127, g = tid >> 7;  // 8 groups
  float v = 0.f;
  for (int b = g; b < NBLK_MAIN; b += 8) v += part2[b * 128 + c];
  red2[g * 128 + c] = v;
  __syncthreads();
  if (g == 0){
    float t = 0.f;
#pragma unroll
    for (int gg = 0; gg < 8; ++gg) t += red2[gg * 128 + c];
    col[c] = t;
  }
  __syncthreads();
  if (tid < 64){
    const float inv = 1.f / (float)N_ATOMS;
    float mu = col[tid] * inv;
    float var = col[64 + tid] * inv - mu * mu;
    float sc = bn2_g[tid] * rsqrtf(var + EPSV);
    stats2[tid] = sc;
    stats2[64 + tid] = bn2_b[tid] - mu * sc;
  }
}

// ---------------- K5: out = softplus(atom_tf + BN2(nbr_sumed)) --------------
__global__ __launch_bounds__(256) void k_final(
    const float* __restrict__ atom_tf, const float* __restrict__ ns,
    const float* __restrict__ stats2, float* __restrict__ out)
{
  int i = blockIdx.x * 256 + threadIdx.x;
  if (i >= N_ATOMS * 64) return;
  int c = i & 63;
  float x = atom_tf[i] + ns[i] * stats2[c] + stats2[64 + c];
  out[i] = softplusf(x);
}

extern "C" void kernel_launch(void* const* d_in, const int* in_sizes, int n_in,
                              void* d_out, int out_size, void* d_ws, size_t ws_size,
                              hipStream_t stream)
{
  const float* atom_in = (const float*)d_in[0];
  const float* nbr_fea = (const float*)d_in[1];
  const float* adj     = (const float*)d_in[2];
  const float* w1 = (const float*)d_in[3];
  const float* b1 = (const float*)d_in[4];
  const float* w2 = (const float*)d_in[5];
  const float* b2 = (const float*)d_in[6];
  const float* tln1_g = (const float*)d_in[7];
  const float* tln1_b = (const float*)d_in[8];
  const float* tln2_g = (const float*)d_in[9];
  const float* tln2_b = (const float*)d_in[10];
  const float* fc_w = (const float*)d_in[11];
  const float* fc_b = (const float*)d_in[12];
  const float* bn1_g = (const float*)d_in[13];
  const float* bn1_b = (const float*)d_in[14];
  const float* bn2_g = (const float*)d_in[15];
  const float* bn2_b = (const float*)d_in[16];
  const int* nbr_idx = (const int*)d_in[17];
  const int* cidx    = (const int*)d_in[18];
  float* out = (float*)d_out;

  char* ws = (char*)d_ws;
  size_t off = 0;
  float* atom_tf = (float*)(ws + off);    off += (size_t)N_ATOMS * 64 * 4;
  unsigned* proj1p = (unsigned*)(ws + off); off += (size_t)N_ATOMS * 64 * 4;
  unsigned* proj2p = (unsigned*)(ws + off); off += (size_t)N_ATOMS * 64 * 4;
  float* nbr_sumed = (float*)(ws + off);  off += (size_t)N_ATOMS * 64 * 4;
  float* part1 = (float*)(ws + off);      off += (size_t)NBLK_MAIN * 256 * 4;
  float* stats1 = (float*)(ws + off);     off += 256 * 4;
  float* part2 = (float*)(ws + off);      off += (size_t)NBLK_MAIN * 128 * 4;
  float* stats2 = (float*)(ws + off);     off += 128 * 4;
  unsigned* gated = (unsigned*)(ws + off);
  const size_t need_gated = off + (size_t)N_ATOMS * M_NBR * 64 * 4;
  const bool use_gated = (ws_size >= need_gated);

  k_transformer<<<B_CRY, 512, 0, stream>>>(atom_in, adj, w1, b1, w2, b2,
      tln1_g, tln1_b, tln2_g, tln2_b, cidx, fc_w, fc_b, atom_tf, proj1p, proj2p);
  if (use_gated){
    k_stats<1><<<NBLK_MAIN, 256, 0, stream>>>(nbr_fea, nbr_idx, fc_w, proj1p,
        proj2p, part1, gated);
    k_stats_fin<<<1, 1024, 0, stream>>>(part1, bn1_g, bn1_b, stats1);
    k_reduce_g<<<NBLK_MAIN, 256, 0, stream>>>(gated, stats1, nbr_sumed, part2);
  } else {
    k_stats<0><<<NBLK_MAIN, 256, 0, stream>>>(nbr_fea, nbr_idx, fc_w, proj1p,
        proj2p, part1, gated);
    k_stats_fin<<<1, 1024, 0, stream>>>(part1, bn1_g, bn1_b, stats1);
    k_reduce_r<<<NBLK_MAIN, 256, 0, stream>>>(nbr_fea, nbr_idx, fc_w, proj1p,
        proj2p, stats1, nbr_sumed, part2);
  }
  k_red_fin<<<1, 1024, 0, stream>>>(part2, bn2_g, bn2_b, stats2);
  k_final<<<(N_ATOMS * 64 + 255) / 256, 256, 0, stream>>>(atom_tf, nbr_sumed, stats2, out);
}

// Round 19
// 539.428 us; speedup vs baseline: 1.2008x; 1.2008x over previous
//
#include <hip/hip_runtime.h>
#include <math.h>

#define N_ATOMS 60000
#define M_NBR   12
#define D_FEA   64
#define NBR_FEA 41
#define B_CRY   1200
#define NA_CRY  50
#define EPSV    1e-5f

#define NBLK_MAIN 2048   // blocks for k_stats (4 waves each)

__device__ __forceinline__ float wsum(float v){
#pragma unroll
  for (int o = 32; o > 0; o >>= 1) v += __shfl_xor(v, o, 64);
  return v;
}
__device__ __forceinline__ float wmax64(float v){
#pragma unroll
  for (int o = 32; o > 0; o >>= 1) v = fmaxf(v, __shfl_xor(v, o, 64));
  return v;
}
__device__ __forceinline__ float softplusf(float x){
  return fmaxf(x, 0.f) + __logf(1.f + __expf(-fabsf(x)));
}
__device__ __forceinline__ float sigmoidf(float x){
  return 1.f / (1.f + __expf(-x));
}
// round-to-nearest-even fp32 -> bf16 bits (low 16)
__device__ __forceinline__ unsigned bf16_rne(float x){
  unsigned u = __float_as_uint(x);
  return (u + 0x7fffu + ((u >> 16) & 1u)) >> 16;
}
__device__ __forceinline__ unsigned pack2(float lo, float hi){
  return bf16_rne(lo) | (bf16_rne(hi) << 16);
}
__device__ __forceinline__ float unlo(unsigned u){ return __uint_as_float(u << 16); }
__device__ __forceinline__ float unhi(unsigned u){ return __uint_as_float(u & 0xffff0000u); }

// ---------------- K1: transformer + fused projections -----------------------
// r18 lesson: row-per-wave + readlane broadcast REGRESSED (276us) -- only
// 50/64 lanes useful, serial readlane->FMA chains. This is the r16 element-
// parallel form (measured 173us) with LDS-traffic tiling:
//  - phase 2: 2x2 score tile/thread (4 reads per 4 FMAs, was 8)
//  - phase 4: 2 rows/thread share s_a[m][d]; s_c reads are wave-uniform
//    broadcasts (nh constant within a wave)
__global__ __launch_bounds__(512, 4) void k_transformer(
    const float* __restrict__ atom_in, const float* __restrict__ adj,
    const float* __restrict__ w1, const float* __restrict__ b1,
    const float* __restrict__ w2, const float* __restrict__ b2,
    const float* __restrict__ g1v, const float* __restrict__ be1,
    const float* __restrict__ g2v, const float* __restrict__ be2,
    const int* __restrict__ cidx, const float* __restrict__ fc_w,
    const float* __restrict__ fc_b, float* __restrict__ atom_tf,
    unsigned* __restrict__ proj1p, unsigned* __restrict__ proj2p)
{
  __shared__ float s_a[NA_CRY * D_FEA];        // src / LN1 / LN2-out
  __shared__ float s_b[D_FEA * (NA_CRY + 1)];  // srcT(stride 51) / x / t
  __shared__ float s_c[NA_CRY * D_FEA];        // scores / h1 / atom_in rows
  __shared__ int   s_gi[NA_CRY];               // gathered atom ids

  const int tid  = threadIdx.x;
  const int b    = blockIdx.x;
  const int lane = tid & 63;
  const int w    = tid >> 6;   // 0..7

  // phase 1: load src (gather) + transposed copy (stride 51); stash ids
  if (tid < NA_CRY) s_gi[tid] = cidx[b * NA_CRY + tid];
  for (int p = tid; p < NA_CRY * D_FEA; p += 512){
    int i = p >> 6, d = p & 63;
    int a = cidx[b * NA_CRY + i];
    float v = atom_in[a * D_FEA + d];
    s_a[p] = v;
    s_b[d * (NA_CRY + 1) + i] = v;
  }
  __syncthreads();

  // phase 2: scores = (src . src^T) * scale * adj, 2x2 tile per thread
  const float scale = 0.125f; // 1/sqrt(64)
  {
    const float* adjb = adj + (size_t)b * NA_CRY * NA_CRY;
    for (int t = tid; t < 625; t += 512){
      int i0 = (t / 25) * 2, j0 = (t % 25) * 2;
      float a00 = 0.f, a01 = 0.f, a10 = 0.f, a11 = 0.f;
#pragma unroll 8
      for (int d = 0; d < D_FEA; ++d){
        float va0 = s_a[i0 * D_FEA + d];
        float va1 = s_a[(i0 + 1) * D_FEA + d];
        float vb0 = s_b[d * (NA_CRY + 1) + j0];
        float vb1 = s_b[d * (NA_CRY + 1) + j0 + 1];
        a00 += va0 * vb0; a01 += va0 * vb1;
        a10 += va1 * vb0; a11 += va1 * vb1;
      }
      s_c[i0 * NA_CRY + j0]           = a00 * scale * adjb[i0 * NA_CRY + j0];
      s_c[i0 * NA_CRY + j0 + 1]       = a01 * scale * adjb[i0 * NA_CRY + j0 + 1];
      s_c[(i0 + 1) * NA_CRY + j0]     = a10 * scale * adjb[(i0 + 1) * NA_CRY + j0];
      s_c[(i0 + 1) * NA_CRY + j0 + 1] = a11 * scale * adjb[(i0 + 1) * NA_CRY + j0 + 1];
    }
  }
  __syncthreads();

  // phase 3: softmax over rows (wave per row)
  for (int r = w; r < NA_CRY; r += 8){
    float v = (lane < NA_CRY) ? s_c[r * NA_CRY + lane] : -1e30f;
    float mx = wmax64(v);
    float e = (lane < NA_CRY) ? __expf(v - mx) : 0.f;
    float s = wsum(e);
    if (lane < NA_CRY) s_c[r * NA_CRY + lane] = e / s;
  }
  __syncthreads();

  // phase 4: x = src + attn @ src -> s_b; 2 rows/thread share s_a[m][d].
  // t>>6 (row-pair id) is constant within a wave -> s_c reads broadcast.
  for (int t = tid; t < 25 * D_FEA; t += 512){
    int nh = t >> 6, d = t & 63;
    int n0 = nh * 2, n1 = n0 + 1;
    float x0 = 0.f, x1 = 0.f;
#pragma unroll 10
    for (int m = 0; m < NA_CRY; ++m){
      float sa = s_a[m * D_FEA + d];
      x0 += s_c[n0 * NA_CRY + m] * sa;
      x1 += s_c[n1 * NA_CRY + m] * sa;
    }
    s_b[n0 * D_FEA + d] = s_a[n0 * D_FEA + d] + x0;
    s_b[n1 * D_FEA + d] = s_a[n1 * D_FEA + d] + x1;
  }
  __syncthreads();

  // phase 5: LN1 -> s_a
  for (int r = w; r < NA_CRY; r += 8){
    float x = s_b[r * D_FEA + lane];
    float mu = wsum(x) * (1.f / 64.f);
    float dx = x - mu;
    float var = wsum(dx * dx) * (1.f / 64.f);
    s_a[r * D_FEA + lane] = dx * rsqrtf(var + EPSV) * g1v[lane] + be1[lane];
  }
  __syncthreads();

  // phase 6: h1 = relu(LN1 @ w1 + b1) -> s_c  (2 rows x 2 k-parities)
  for (int n0 = w * 2; n0 < NA_CRY; n0 += 16){
    const int n1 = n0 + 1;
    float x00 = 0.f, x01 = 0.f, x10 = 0.f, x11 = 0.f;
#pragma unroll
    for (int k = 0; k < D_FEA; k += 2){
      float wv0 = w1[k * D_FEA + lane];
      float wv1 = w1[(k + 1) * D_FEA + lane];
      x00 += s_a[n0 * D_FEA + k] * wv0;
      x01 += s_a[n0 * D_FEA + k + 1] * wv1;
      x10 += s_a[n1 * D_FEA + k] * wv0;
      x11 += s_a[n1 * D_FEA + k + 1] * wv1;
    }
    float bb = b1[lane];
    s_c[n0 * D_FEA + lane] = fmaxf(bb + x00 + x01, 0.f);
    s_c[n1 * D_FEA + lane] = fmaxf(bb + x10 + x11, 0.f);
  }
  __syncthreads();

  // phase 7: t = LN1 + h1 @ w2 + b2 -> s_b  (4 chains)
  for (int n0 = w * 2; n0 < NA_CRY; n0 += 16){
    const int n1 = n0 + 1;
    float x00 = 0.f, x01 = 0.f, x10 = 0.f, x11 = 0.f;
#pragma unroll
    for (int k = 0; k < D_FEA; k += 2){
      float wv0 = w2[k * D_FEA + lane];
      float wv1 = w2[(k + 1) * D_FEA + lane];
      x00 += s_c[n0 * D_FEA + k] * wv0;
      x01 += s_c[n0 * D_FEA + k + 1] * wv1;
      x10 += s_c[n1 * D_FEA + k] * wv0;
      x11 += s_c[n1 * D_FEA + k + 1] * wv1;
    }
    float bb = b2[lane];
    s_b[n0 * D_FEA + lane] = s_a[n0 * D_FEA + lane] + bb + x00 + x01;
    s_b[n1 * D_FEA + lane] = s_a[n1 * D_FEA + lane] + bb + x10 + x11;
  }
  __syncthreads();

  // phase 8: LN2 -> atom_tf AND s_a (kept for fused projection)
  for (int r = w; r < NA_CRY; r += 8){
    float x = s_b[r * D_FEA + lane];
    float mu = wsum(x) * (1.f / 64.f);
    float dx = x - mu;
    float var = wsum(dx * dx) * (1.f / 64.f);
    float res = dx * rsqrtf(var + EPSV) * g2v[lane] + be2[lane];
    atom_tf[(b * NA_CRY + r) * D_FEA + lane] = res;
    s_a[r * D_FEA + lane] = res;
  }
  __syncthreads();

  // phase 9a: re-gather atom_in rows into s_c (h1 dead)
  for (int p = tid; p < NA_CRY * D_FEA; p += 512){
    int i = p >> 6, d = p & 63;
    s_c[p] = atom_in[(size_t)s_gi[i] * D_FEA + d];
  }
  __syncthreads();

  // phase 9b: fused projections, 4 rows share each fc_w load quartet.
  for (int n0 = w * 4; n0 < NA_CRY; n0 += 32){
    const int nb = (n0 + 1 < NA_CRY) ? n0 + 1 : NA_CRY - 1;
    const int nc = (n0 + 2 < NA_CRY) ? n0 + 2 : NA_CRY - 1;
    const int nd = (n0 + 3 < NA_CRY) ? n0 + 3 : NA_CRY - 1;
    const int c = lane;
    const float bb0 = fc_b[c], bb1 = fc_b[64 + c];
    float A1 = bb0, A2 = bb1, A3 = 0.f, A4 = 0.f;
    float B1 = bb0, B2 = bb1, B3 = 0.f, B4 = 0.f;
    float C1 = bb0, C2 = bb1, C3 = 0.f, C4 = 0.f;
    float D1 = bb0, D2 = bb1, D3 = 0.f, D4 = 0.f;
#pragma unroll 4
    for (int k = 0; k < D_FEA; ++k){
      float w0 = fc_w[k * 128 + c];
      float w6 = fc_w[k * 128 + 64 + c];
      float v0 = fc_w[(64 + k) * 128 + c];
      float v6 = fc_w[(64 + k) * 128 + 64 + c];
      float ta = s_a[n0 * 64 + k], tb = s_a[nb * 64 + k];
      float tc = s_a[nc * 64 + k], td = s_a[nd * 64 + k];
      float sa = s_c[n0 * 64 + k], sb = s_c[nb * 64 + k];
      float sc = s_c[nc * 64 + k], sd = s_c[nd * 64 + k];
      A1 += ta * w0; A2 += ta * w6; A3 += sa * v0; A4 += sa * v6;
      B1 += tb * w0; B2 += tb * w6; B3 += sb * v0; B4 += sb * v6;
      C1 += tc * w0; C2 += tc * w6; C3 += sc * v0; C4 += sc * v6;
      D1 += td * w0; D2 += td * w6; D3 += sd * v0; D4 += sd * v6;
    }
    proj1p[(size_t)(b * NA_CRY + n0) * 64 + c] = pack2(A1, A2);
    proj2p[(size_t)s_gi[n0] * 64 + c] = pack2(A3, A4);
    if (n0 + 1 < NA_CRY){
      proj1p[(size_t)(b * NA_CRY + nb) * 64 + c] = pack2(B1, B2);
      proj2p[(size_t)s_gi[nb] * 64 + c] = pack2(B3, B4);
    }
    if (n0 + 2 < NA_CRY){
      proj1p[(size_t)(b * NA_CRY + nc) * 64 + c] = pack2(C1, C2);
      proj2p[(size_t)s_gi[nc] * 64 + c] = pack2(C3, C4);
    }
    if (n0 + 3 < NA_CRY){
      proj1p[(size_t)(b * NA_CRY + nd) * 64 + c] = pack2(D1, D2);
      proj2p[(size_t)s_gi[nd] * 64 + c] = pack2(D3, D4);
    }
  }
}

// ---------------- K3: BN1 stats + store pre-BN g (bf16x2) -------------------
// (r16 proven: global_load_lds staging into wave-private dbuf LDS tile.)
#define LOADRW(MM) unsigned rw##MM = proj2p[(size_t)__builtin_amdgcn_readfirstlane(jrow[MM]) * 64 + lane];

#define STAGE(AA, BUF) { \
    const float* srcp = nbr_fea + (size_t)(AA) * (M_NBR * NBR_FEA); \
    float* dstp = s_frow + (w * 2 + (BUF)) * 512; \
    _Pragma("unroll") \
    for (int t = 0; t < 7; ++t) \
      __builtin_amdgcn_global_load_lds(srcp + t * 64 + lane, dstp + t * 64, 4, 0, 0); \
    if (lane < 44) \
      __builtin_amdgcn_global_load_lds(srcp + 448 + lane, dstp + 448, 4, 0, 0); \
  }

#define GBODY(MM) { \
    float g0 = p10 + unlo(rw##MM); \
    float g1 = p11 + unhi(rw##MM); \
    _Pragma("unroll") \
    for (int k = 0; k < NBR_FEA; ++k){ \
      float aa = fr[MM * NBR_FEA + k]; \
      g0 += aa * unlo(wbp[k]); \
      g1 += aa * unhi(wbp[k]); \
    } \
    if (STORE) gated[(size_t)(base + MM) * 64 + lane] = pack2(g0, g1); \
    s0 += g0; q0 += g0 * g0; \
    s1 += g1; q1 += g1 * g1; }

template<int STORE>
__global__ __launch_bounds__(256) void k_stats(
    const float* __restrict__ nbr_fea, const int* __restrict__ nbr_idx,
    const float* __restrict__ fc_w, const unsigned* __restrict__ proj1p,
    const unsigned* __restrict__ proj2p, float* __restrict__ part1,
    unsigned* __restrict__ gated)
{
  __shared__ float red[1024];
  __shared__ float s_frow[4 * 2 * 512];  // 4 waves x double-buffer x 512 floats
  const int tid = threadIdx.x, lane = tid & 63, w = tid >> 6;

  unsigned wbp[NBR_FEA];
#pragma unroll
  for (int k = 0; k < NBR_FEA; ++k){
    float w0 = fc_w[(128 + k) * 128 + lane];
    float w1 = fc_w[(128 + k) * 128 + 64 + lane];
    wbp[k] = pack2(w0, w1);
  }

  const int gw = blockIdx.x * 4 + w, nw = gridDim.x * 4;
  const int q = N_ATOMS / nw, rr = N_ATOMS % nw;
  const int a0 = gw * q + (gw < rr ? gw : rr);
  const int a1 = a0 + q + (gw < rr ? 1 : 0);
  float s0 = 0.f, s1 = 0.f, q0 = 0.f, q1 = 0.f;
  int cur = 0;
  if (a0 < a1){ STAGE(a0, 0); }
  for (int a = a0; a < a1; ++a){
    const int au = __builtin_amdgcn_readfirstlane(a);
    const int base = au * M_NBR;
    const int* jrow = nbr_idx + base;            // uniform -> s_load (tiny)
    unsigned p1v = proj1p[(size_t)au * 64 + lane];
    LOADRW(0) LOADRW(1) LOADRW(2) LOADRW(3) LOADRW(4) LOADRW(5)
    LOADRW(6) LOADRW(7) LOADRW(8) LOADRW(9) LOADRW(10) LOADRW(11)
    const int anext = (a + 1 < a1) ? (a + 1) : a;
    STAGE(anext, cur ^ 1);                       // 8 newest vmem ops
    asm volatile("s_waitcnt vmcnt(8)" ::: "memory");  // drain rw/p1 + prior stage
    const float* fr = s_frow + (w * 2 + cur) * 512;
    const float p10 = unlo(p1v), p11 = unhi(p1v);
    GBODY(0) GBODY(1) GBODY(2) GBODY(3) GBODY(4) GBODY(5)
    GBODY(6) GBODY(7) GBODY(8) GBODY(9) GBODY(10) GBODY(11)
    cur ^= 1;
  }
  red[w * 256 + lane]        = s0;
  red[w * 256 + 64 + lane]   = s1;
  red[w * 256 + 128 + lane]  = q0;
  red[w * 256 + 192 + lane]  = q1;
  __syncthreads();
  float v = red[tid] + red[256 + tid] + red[512 + tid] + red[768 + tid];
  part1[blockIdx.x * 256 + tid] = v;   // [0:128]=sum(ch), [128:256]=sumsq(ch)
}

// finish BN1 stats: stats1[c]=scale, stats1[128+c]=shift
__global__ __launch_bounds__(1024) void k_stats_fin(
    const float* __restrict__ part1, const float* __restrict__ bn1_g,
    const float* __restrict__ bn1_b, float* __restrict__ stats1)
{
  __shared__ float red2[4 * 256];
  __shared__ float col[256];
  const int tid = threadIdx.x;
  const int c = tid & 255, g = tid >> 8;  // 4 groups
  float v = 0.f;
  for (int b = g; b < NBLK_MAIN; b += 4) v += part1[b * 256 + c];
  red2[g * 256 + c] = v;
  __syncthreads();
  if (g == 0) col[c] = red2[c] + red2[256 + c] + red2[512 + c] + red2[768 + c];
  __syncthreads();
  if (tid < 128){
    const float inv = 1.f / (float)(N_ATOMS * M_NBR);
    float mu = col[tid] * inv;
    float var = col[128 + tid] * inv - mu * mu;
    float sc = bn1_g[tid] * rsqrtf(var + EPSV);
    stats1[tid] = sc;
    stats1[128 + tid] = bn1_b[tid] - mu * sc;
  }
}

// ---------------- K4a (gated path): streaming BN1+gate+sum ------------------
__global__ __launch_bounds__(256) void k_reduce_g(
    const unsigned* __restrict__ gated, const float* __restrict__ stats1,
    float* __restrict__ nbr_sumed, float* __restrict__ part2)
{
  __shared__ float red[512];
  const int tid = threadIdx.x, lane = tid & 63, w = tid >> 6;
  const float sc0 = stats1[lane],       sc1 = stats1[64 + lane];
  const float tc0 = stats1[128 + lane], tc1 = stats1[192 + lane];
  const int wg = blockIdx.x * 4 + w, nw = gridDim.x * 4;
  float bs = 0.f, bq = 0.f;
  for (int a = wg; a < N_ATOMS; a += nw){
    const size_t base = (size_t)a * M_NBR * 64 + lane;
    float acc = 0.f;
#pragma unroll
    for (int m = 0; m < M_NBR; ++m){
      unsigned gv = gated[base + m * 64];
      acc += sigmoidf(unlo(gv) * sc0 + tc0) * softplusf(unhi(gv) * sc1 + tc1);
    }
    nbr_sumed[(size_t)a * 64 + lane] = acc;
    bs += acc; bq += acc * acc;
  }
  red[w * 128 + lane]      = bs;
  red[w * 128 + 64 + lane] = bq;
  __syncthreads();
  if (tid < 128){
    float v = red[tid] + red[128 + tid] + red[256 + tid] + red[384 + tid];
    part2[blockIdx.x * 128 + tid] = v;  // [0:64]=sum, [64:128]=sumsq
  }
}

// ---------------- K4b (fallback): recompute g, BN1, gate, sum ---------------
#define GBODYR(MM) { \
    const float* frow = nbr_fea + (size_t)(base + MM) * NBR_FEA; \
    float g0 = p10 + unlo(rw##MM); \
    float g1 = p11 + unhi(rw##MM); \
    _Pragma("unroll") \
    for (int k = 0; k < NBR_FEA; ++k){ \
      float aa = frow[k]; \
      g0 += aa * unlo(wbp[k]); \
      g1 += aa * unhi(wbp[k]); \
    } \
    acc += sigmoidf(g0 * sc0 + tc0) * softplusf(g1 * sc1 + tc1); }

__global__ __launch_bounds__(256) void k_reduce_r(
    const float* __restrict__ nbr_fea, const int* __restrict__ nbr_idx,
    const float* __restrict__ fc_w, const unsigned* __restrict__ proj1p,
    const unsigned* __restrict__ proj2p, const float* __restrict__ stats1,
    float* __restrict__ nbr_sumed, float* __restrict__ part2)
{
  __shared__ float red[512];
  const int tid = threadIdx.x, lane = tid & 63, w = tid >> 6;
  unsigned wbp[NBR_FEA];
#pragma unroll
  for (int k = 0; k < NBR_FEA; ++k){
    float w0 = fc_w[(128 + k) * 128 + lane];
    float w1 = fc_w[(128 + k) * 128 + 64 + lane];
    wbp[k] = pack2(w0, w1);
  }
  const float sc0 = stats1[lane],       sc1 = stats1[64 + lane];
  const float tc0 = stats1[128 + lane], tc1 = stats1[192 + lane];
  const int gw = blockIdx.x * 4 + w, nw = gridDim.x * 4;
  const int q = N_ATOMS / nw, rr = N_ATOMS % nw;
  const int a0 = gw * q + (gw < rr ? gw : rr);
  const int a1 = a0 + q + (gw < rr ? 1 : 0);
  float bs = 0.f, bq = 0.f;
  for (int a = a0; a < a1; ++a){
    const int au = __builtin_amdgcn_readfirstlane(a);
    const int base = au * M_NBR;
    const int* jrow = nbr_idx + base;
    unsigned p1v = proj1p[(size_t)au * 64 + lane];
    LOADRW(0) LOADRW(1) LOADRW(2) LOADRW(3) LOADRW(4) LOADRW(5)
    LOADRW(6) LOADRW(7) LOADRW(8) LOADRW(9) LOADRW(10) LOADRW(11)
    const float p10 = unlo(p1v), p11 = unhi(p1v);
    float acc = 0.f;
    GBODYR(0) GBODYR(1) GBODYR(2) GBODYR(3) GBODYR(4) GBODYR(5)
    GBODYR(6) GBODYR(7) GBODYR(8) GBODYR(9) GBODYR(10) GBODYR(11)
    nbr_sumed[(size_t)au * 64 + lane] = acc;
    bs += acc; bq += acc * acc;
  }
  red[w * 128 + lane]      = bs;
  red[w * 128 + 64 + lane] = bq;
  __syncthreads();
  if (tid < 128){
    float v = red[tid] + red[128 + tid] + red[256 + tid] + red[384 + tid];
    part2[blockIdx.x * 128 + tid] = v;
  }
}

// finish BN2 stats
__global__ __launch_bounds__(1024) void k_red_fin(
    const float* __restrict__ part2, const float* __restrict__ bn2_g,
    const float* __restrict__ bn2_b, float* __restrict__ stats2)
{
  __shared__ float red2[8 * 128];
  __shared__ float col[128];
  const int tid = threadIdx.x;
  const int c = tid & 127, g = tid >> 7;  // 8 groups
  float v = 0.f;
  for (int b = g; b < NBLK_MAIN; b += 8) v += part2[b * 128 + c];
  red2[g * 128 + c] = v;
  __syncthreads();
  if (g == 0){
    float t = 0.f;
#pragma unroll
    for (int gg = 0; gg < 8; ++gg) t += red2[gg * 128 + c];
    col[c] = t;
  }
  __syncthreads();
  if (tid < 64){
    const float inv = 1.f / (float)N_ATOMS;
    float mu = col[tid] * inv;
    float var = col[64 + tid] * inv - mu * mu;
    float sc = bn2_g[tid] * rsqrtf(var + EPSV);
    stats2[tid] = sc;
    stats2[64 + tid] = bn2_b[tid] - mu * sc;
  }
}

// ---------------- K5: out = softplus(atom_tf + BN2(nbr_sumed)) --------------
__global__ __launch_bounds__(256) void k_final(
    const float* __restrict__ atom_tf, const float* __restrict__ ns,
    const float* __restrict__ stats2, float* __restrict__ out)
{
  int i = blockIdx.x * 256 + threadIdx.x;
  if (i >= N_ATOMS * 64) return;
  int c = i & 63;
  float x = atom_tf[i] + ns[i] * stats2[c] + stats2[64 + c];
  out[i] = softplusf(x);
}

extern "C" void kernel_launch(void* const* d_in, const int* in_sizes, int n_in,
                              void* d_out, int out_size, void* d_ws, size_t ws_size,
                              hipStream_t stream)
{
  const float* atom_in = (const float*)d_in[0];
  const float* nbr_fea = (const float*)d_in[1];
  const float* adj     = (const float*)d_in[2];
  const float* w1 = (const float*)d_in[3];
  const float* b1 = (const float*)d_in[4];
  const float* w2 = (const float*)d_in[5];
  const float* b2 = (const float*)d_in[6];
  const float* tln1_g = (const float*)d_in[7];
  const float* tln1_b = (const float*)d_in[8];
  const float* tln2_g = (const float*)d_in[9];
  const float* tln2_b = (const float*)d_in[10];
  const float* fc_w = (const float*)d_in[11];
  const float* fc_b = (const float*)d_in[12];
  const float* bn1_g = (const float*)d_in[13];
  const float* bn1_b = (const float*)d_in[14];
  const float* bn2_g = (const float*)d_in[15];
  const float* bn2_b = (const float*)d_in[16];
  const int* nbr_idx = (const int*)d_in[17];
  const int* cidx    = (const int*)d_in[18];
  float* out = (float*)d_out;

  char* ws = (char*)d_ws;
  size_t off = 0;
  float* atom_tf = (float*)(ws + off);    off += (size_t)N_ATOMS * 64 * 4;
  unsigned* proj1p = (unsigned*)(ws + off); off += (size_t)N_ATOMS * 64 * 4;
  unsigned* proj2p = (unsigned*)(ws + off); off += (size_t)N_ATOMS * 64 * 4;
  float* nbr_sumed = (float*)(ws + off);  off += (size_t)N_ATOMS * 64 * 4;
  float* part1 = (float*)(ws + off);      off += (size_t)NBLK_MAIN * 256 * 4;
  float* stats1 = (float*)(ws + off);     off += 256 * 4;
  float* part2 = (float*)(ws + off);      off += (size_t)NBLK_MAIN * 128 * 4;
  float* stats2 = (float*)(ws + off);     off += 128 * 4;
  unsigned* gated = (unsigned*)(ws + off);
  const size_t need_gated = off + (size_t)N_ATOMS * M_NBR * 64 * 4;
  const bool use_gated = (ws_size >= need_gated);

  k_transformer<<<B_CRY, 512, 0, stream>>>(atom_in, adj, w1, b1, w2, b2,
      tln1_g, tln1_b, tln2_g, tln2_b, cidx, fc_w, fc_b, atom_tf, proj1p, proj2p);
  if (use_gated){
    k_stats<1><<<NBLK_MAIN, 256, 0, stream>>>(nbr_fea, nbr_idx, fc_w, proj1p,
        proj2p, part1, gated);
    k_stats_fin<<<1, 1024, 0, stream>>>(part1, bn1_g, bn1_b, stats1);
    k_reduce_g<<<NBLK_MAIN, 256, 0, stream>>>(gated, stats1, nbr_sumed, part2);
  } else {
    k_stats<0><<<NBLK_MAIN, 256, 0, stream>>>(nbr_fea, nbr_idx, fc_w, proj1p,
        proj2p, part1, gated);
    k_stats_fin<<<1, 1024, 0, stream>>>(part1, bn1_g, bn1_b, stats1);
    k_reduce_r<<<NBLK_MAIN, 256, 0, stream>>>(nbr_fea, nbr_idx, fc_w, proj1p,
        proj2p, stats1, nbr_sumed, part2);
  }
  k_red_fin<<<1, 1024, 0, stream>>>(part2, bn2_g, bn2_b, stats2);
  k_final<<<(N_ATOMS * 64 + 255) / 256, 256, 0, stream>>>(atom_tf, nbr_sumed, stats2, out);
}